// Round 1
// baseline (889.243 us; speedup 1.0000x reference)
//
#include <hip/hip_runtime.h>
#include <hip/hip_bf16.h>

#define NN 50000
#define NE 800000
#define DN 64
#define DE 32
#define HID 128

// LDS row strides (bf16 elements), padded to break power-of-2 bank patterns
#define SA 72
#define SH 136

typedef __attribute__((ext_vector_type(8))) short bf16x8;
typedef __attribute__((ext_vector_type(4))) float f32x4;

__device__ __forceinline__ short f2bf(float f) {
    union { float f; unsigned u; } v; v.f = f;
    unsigned r = v.u + 0x7fffu + ((v.u >> 16) & 1u);
    return (short)(r >> 16);
}
__device__ __forceinline__ int pk(float a, float b) {
    return ((int)f2bf(a) & 0xffff) | ((int)f2bf(b) << 16);
}

// ---- weight prep: f32 [in][out] -> bf16 transposed [out][in] in workspace ----
// layout (bf16 elements):
//   Wt_n1 @ 0      : [128][64]
//   Wt_n2 @ 8192   : [128][128]
//   Wt_e1 @ 24576  : [128][32]
//   Wt_e2 @ 28672  : [128][128]
//   Wt_c  @ 45056  : [64][128]
//   Wt_ue @ 53248  : [32][64]   (end 55296)
__global__ void prep_weights(const float* __restrict__ Wn1, const float* __restrict__ Wn2,
                             const float* __restrict__ We1, const float* __restrict__ We2,
                             const float* __restrict__ Wc,  const float* __restrict__ Wue,
                             short* __restrict__ wb) {
    int i = blockIdx.x * 256 + threadIdx.x;
    if (i < 8192)       { int o = i >> 6, k = i & 63;                 wb[i] = f2bf(Wn1[k * 128 + o]); }
    else if (i < 24576) { int j = i - 8192;  int o = j >> 7, k = j & 127; wb[i] = f2bf(Wn2[k * 128 + o]); }
    else if (i < 28672) { int j = i - 24576; int o = j >> 5, k = j & 31;  wb[i] = f2bf(We1[k * 128 + o]); }
    else if (i < 45056) { int j = i - 28672; int o = j >> 7, k = j & 127; wb[i] = f2bf(We2[k * 128 + o]); }
    else if (i < 53248) { int j = i - 45056; int o = j >> 7, k = j & 127; wb[i] = f2bf(Wc[k * 64 + o]); }
    else if (i < 55296) { int j = i - 53248; int o = j >> 6, k = j & 63;  wb[i] = f2bf(Wue[k * 32 + o]); }
}

// ---- fused message kernel: tile of 128 edges per block, 8 waves ----
__global__ __launch_bounds__(512) void msg_kernel(
    const float* __restrict__ node_h, const float* __restrict__ edge_h,
    const int* __restrict__ src, const int* __restrict__ dst,
    const short* __restrict__ wts,
    const float* __restrict__ b_n1, const float* __restrict__ b_n2,
    const float* __restrict__ b_e1, const float* __restrict__ b_e2,
    const float* __restrict__ b_c,
    float* __restrict__ h_new)
{
    __shared__ short sA[128 * SA];
    __shared__ short sH[128 * SH];
    __shared__ int   sDst[128];

    const short* Wn1 = wts;
    const short* Wn2 = wts + 8192;
    const short* We1 = wts + 24576;
    const short* We2 = wts + 28672;
    const short* Wc  = wts + 45056;

    const int tid  = threadIdx.x;
    const int base = blockIdx.x * 128;
    const int lane = tid & 63;
    const int lr   = lane & 15;
    const int lg   = lane >> 4;
    const int r0   = (tid >> 6) * 16;

    if (tid < 128) sDst[tid] = dst[base + tid];

    // stage gathered h_src tile [128][64] -> bf16
    {
        int row = tid >> 2;
        int kq  = (tid & 3) << 4;
        const float4* p = (const float4*)(node_h + (size_t)src[base + row] * DN + kq);
        float4 v0 = p[0], v1 = p[1], v2 = p[2], v3 = p[3];
        int4 w0, w1;
        w0.x = pk(v0.x, v0.y); w0.y = pk(v0.z, v0.w);
        w0.z = pk(v1.x, v1.y); w0.w = pk(v1.z, v1.w);
        w1.x = pk(v2.x, v2.y); w1.y = pk(v2.z, v2.w);
        w1.z = pk(v3.x, v3.y); w1.w = pk(v3.z, v3.w);
        *(int4*)&sA[row * SA + kq]     = w0;
        *(int4*)&sA[row * SA + kq + 8] = w1;
    }
    __syncthreads();

    // G1: H1n = relu(h_src @ Wn1 + b_n1) -> sH (bf16)
    {
        f32x4 acc[8];
        #pragma unroll
        for (int t = 0; t < 8; t++) acc[t] = (f32x4){0.f, 0.f, 0.f, 0.f};
        #pragma unroll
        for (int k0 = 0; k0 < 64; k0 += 32) {
            bf16x8 a = *(const bf16x8*)&sA[(r0 + lr) * SA + k0 + lg * 8];
            #pragma unroll
            for (int t = 0; t < 8; t++) {
                bf16x8 b = *(const bf16x8*)&Wn1[(t * 16 + lr) * 64 + k0 + lg * 8];
                acc[t] = __builtin_amdgcn_mfma_f32_16x16x32_bf16(a, b, acc[t], 0, 0, 0);
            }
        }
        #pragma unroll
        for (int t = 0; t < 8; t++) {
            float bias = b_n1[t * 16 + lr];
            #pragma unroll
            for (int i = 0; i < 4; i++) {
                float v = acc[t][i] + bias;
                v = v > 0.f ? v : 0.f;
                sH[(r0 + lg * 4 + i) * SH + t * 16 + lr] = f2bf(v);
            }
        }
    }
    __syncthreads();

    // stage edge_h tile [128][32] into sA (free after G1)
    {
        int row = tid >> 2;
        int seg = (tid & 3) << 3;
        const float4* p = (const float4*)(edge_h + (size_t)(base + row) * DE + seg);
        float4 v0 = p[0], v1 = p[1];
        int4 w0;
        w0.x = pk(v0.x, v0.y); w0.y = pk(v0.z, v0.w);
        w0.z = pk(v1.x, v1.y); w0.w = pk(v1.z, v1.w);
        *(int4*)&sA[row * SA + seg] = w0;
    }

    // G2: m1 = H1n @ Wn2 + b_n2 (keep in registers)
    f32x4 m1[8];
    {
        #pragma unroll
        for (int t = 0; t < 8; t++) m1[t] = (f32x4){0.f, 0.f, 0.f, 0.f};
        #pragma unroll
        for (int k0 = 0; k0 < 128; k0 += 32) {
            bf16x8 a = *(const bf16x8*)&sH[(r0 + lr) * SH + k0 + lg * 8];
            #pragma unroll
            for (int t = 0; t < 8; t++) {
                bf16x8 b = *(const bf16x8*)&Wn2[(t * 16 + lr) * 128 + k0 + lg * 8];
                m1[t] = __builtin_amdgcn_mfma_f32_16x16x32_bf16(a, b, m1[t], 0, 0, 0);
            }
        }
        #pragma unroll
        for (int t = 0; t < 8; t++) {
            float bias = b_n2[t * 16 + lr];
            #pragma unroll
            for (int i = 0; i < 4; i++) m1[t][i] += bias;
        }
    }
    __syncthreads();  // edge staging visible; sH free to overwrite

    // G3: H1e = relu(edge_h @ We1 + b_e1) -> sH
    {
        f32x4 acc[8];
        #pragma unroll
        for (int t = 0; t < 8; t++) acc[t] = (f32x4){0.f, 0.f, 0.f, 0.f};
        bf16x8 a = *(const bf16x8*)&sA[(r0 + lr) * SA + lg * 8];
        #pragma unroll
        for (int t = 0; t < 8; t++) {
            bf16x8 b = *(const bf16x8*)&We1[(t * 16 + lr) * 32 + lg * 8];
            acc[t] = __builtin_amdgcn_mfma_f32_16x16x32_bf16(a, b, acc[t], 0, 0, 0);
        }
        #pragma unroll
        for (int t = 0; t < 8; t++) {
            float bias = b_e1[t * 16 + lr];
            #pragma unroll
            for (int i = 0; i < 4; i++) {
                float v = acc[t][i] + bias;
                v = v > 0.f ? v : 0.f;
                sH[(r0 + lg * 4 + i) * SH + t * 16 + lr] = f2bf(v);
            }
        }
    }
    __syncthreads();

    // G4: m2 = H1e @ We2 + b_e2 ; m = m1 * m2 -> sH (bf16)
    {
        f32x4 acc[8];
        #pragma unroll
        for (int t = 0; t < 8; t++) acc[t] = (f32x4){0.f, 0.f, 0.f, 0.f};
        #pragma unroll
        for (int k0 = 0; k0 < 128; k0 += 32) {
            bf16x8 a = *(const bf16x8*)&sH[(r0 + lr) * SH + k0 + lg * 8];
            #pragma unroll
            for (int t = 0; t < 8; t++) {
                bf16x8 b = *(const bf16x8*)&We2[(t * 16 + lr) * 128 + k0 + lg * 8];
                acc[t] = __builtin_amdgcn_mfma_f32_16x16x32_bf16(a, b, acc[t], 0, 0, 0);
            }
        }
        __syncthreads();  // all sH reads done before overwrite
        #pragma unroll
        for (int t = 0; t < 8; t++) {
            float bias = b_e2[t * 16 + lr];
            #pragma unroll
            for (int i = 0; i < 4; i++) {
                float mv = m1[t][i] * (acc[t][i] + bias);
                sH[(r0 + lg * 4 + i) * SH + t * 16 + lr] = f2bf(mv);
            }
        }
    }
    __syncthreads();

    // G5: out = tanh(m @ Wc + b_c) ; atomic scatter to h_new[dst]
    {
        f32x4 acc[4];
        #pragma unroll
        for (int t = 0; t < 4; t++) acc[t] = (f32x4){0.f, 0.f, 0.f, 0.f};
        #pragma unroll
        for (int k0 = 0; k0 < 128; k0 += 32) {
            bf16x8 a = *(const bf16x8*)&sH[(r0 + lr) * SH + k0 + lg * 8];
            #pragma unroll
            for (int t = 0; t < 4; t++) {
                bf16x8 b = *(const bf16x8*)&Wc[(t * 16 + lr) * 128 + k0 + lg * 8];
                acc[t] = __builtin_amdgcn_mfma_f32_16x16x32_bf16(a, b, acc[t], 0, 0, 0);
            }
        }
        #pragma unroll
        for (int t = 0; t < 4; t++) {
            float bias = b_c[t * 16 + lr];
            #pragma unroll
            for (int i = 0; i < 4; i++) {
                float v = tanhf(acc[t][i] + bias);
                int row = r0 + lg * 4 + i;
                atomicAdd(&h_new[(size_t)sDst[row] * DN + t * 16 + lr], v);
            }
        }
    }
}

// ---- edge EMA kernel ----
__global__ __launch_bounds__(512) void edge_kernel(
    const float* __restrict__ edge_h, const int* __restrict__ src, const int* __restrict__ dst,
    const float* __restrict__ h_new, const short* __restrict__ wts, float* __restrict__ e_new)
{
    __shared__ short sP[128 * SA];
    const short* Wue = wts + 53248;  // [32][64]

    const int tid  = threadIdx.x;
    const int base = blockIdx.x * 128;
    const int lane = tid & 63;
    const int lr   = lane & 15;
    const int lg   = lane >> 4;
    const int r0   = (tid >> 6) * 16;

    {
        int row = tid >> 2;
        int kq  = (tid & 3) << 4;
        int s = src[base + row], d = dst[base + row];
        const float4* ps = (const float4*)(h_new + (size_t)s * DN + kq);
        const float4* pd = (const float4*)(h_new + (size_t)d * DN + kq);
        float4 a0 = ps[0], a1 = ps[1], a2 = ps[2], a3 = ps[3];
        float4 b0 = pd[0], b1 = pd[1], b2 = pd[2], b3 = pd[3];
        int4 w0, w1;
        w0.x = pk(a0.x * b0.x, a0.y * b0.y); w0.y = pk(a0.z * b0.z, a0.w * b0.w);
        w0.z = pk(a1.x * b1.x, a1.y * b1.y); w0.w = pk(a1.z * b1.z, a1.w * b1.w);
        w1.x = pk(a2.x * b2.x, a2.y * b2.y); w1.y = pk(a2.z * b2.z, a2.w * b2.w);
        w1.z = pk(a3.x * b3.x, a3.y * b3.y); w1.w = pk(a3.z * b3.z, a3.w * b3.w);
        *(int4*)&sP[row * SA + kq]     = w0;
        *(int4*)&sP[row * SA + kq + 8] = w1;
    }
    __syncthreads();

    f32x4 acc[2];
    #pragma unroll
    for (int t = 0; t < 2; t++) acc[t] = (f32x4){0.f, 0.f, 0.f, 0.f};
    #pragma unroll
    for (int k0 = 0; k0 < 64; k0 += 32) {
        bf16x8 a = *(const bf16x8*)&sP[(r0 + lr) * SA + k0 + lg * 8];
        #pragma unroll
        for (int t = 0; t < 2; t++) {
            bf16x8 b = *(const bf16x8*)&Wue[(t * 16 + lr) * 64 + k0 + lg * 8];
            acc[t] = __builtin_amdgcn_mfma_f32_16x16x32_bf16(a, b, acc[t], 0, 0, 0);
        }
    }
    #pragma unroll
    for (int t = 0; t < 2; t++) {
        #pragma unroll
        for (int i = 0; i < 4; i++) {
            int row = r0 + lg * 4 + i;
            size_t off = (size_t)(base + row) * DE + t * 16 + lr;
            e_new[off] = 0.8f * edge_h[off] + 0.2f * acc[t][i];
        }
    }
}

extern "C" void kernel_launch(void* const* d_in, const int* in_sizes, int n_in,
                              void* d_out, int out_size, void* d_ws, size_t ws_size,
                              hipStream_t stream) {
    const float* node_h = (const float*)d_in[0];
    const float* edge_h = (const float*)d_in[1];
    const int*   src    = (const int*)d_in[2];
    const int*   dst    = (const int*)d_in[3];
    const float* Wn1 = (const float*)d_in[4];
    const float* bn1 = (const float*)d_in[5];
    const float* Wn2 = (const float*)d_in[6];
    const float* bn2 = (const float*)d_in[7];
    const float* We1 = (const float*)d_in[8];
    const float* be1 = (const float*)d_in[9];
    const float* We2 = (const float*)d_in[10];
    const float* be2 = (const float*)d_in[11];
    const float* Wc  = (const float*)d_in[12];
    const float* bc  = (const float*)d_in[13];
    const float* Wue = (const float*)d_in[14];

    float* h_new = (float*)d_out;
    float* e_new = h_new + (size_t)NN * DN;
    short* wts   = (short*)d_ws;

    prep_weights<<<216, 256, 0, stream>>>(Wn1, Wn2, We1, We2, Wc, Wue, wts);
    hipMemcpyAsync(h_new, node_h, (size_t)NN * DN * sizeof(float),
                   hipMemcpyDeviceToDevice, stream);
    msg_kernel<<<NE / 128, 512, 0, stream>>>(node_h, edge_h, src, dst, wts,
                                             bn1, bn2, be1, be2, bc, h_new);
    edge_kernel<<<NE / 128, 512, 0, stream>>>(edge_h, src, dst, h_new, wts, e_new);
}